// Round 5
// baseline (1373.122 us; speedup 1.0000x reference)
//
#include <hip/hip_runtime.h>

#define C 4096
#define NROWS 16384
#define NBLK 1024
#define TPB 256
#define RPB 16        // rows per block (NROWS/NBLK)
#define CROWS 4       // rows 12..15 cached in registers between phase 1 and 4

typedef float f32x4 __attribute__((ext_vector_type(4)));

// Grid barrier: ticket counter, round base = (t/NBLK)*NBLK. REQUIRES counter
// to start at a multiple of NBLK -> kernel_launch memsets it to 0 each call
// (R4 deadlock root cause: 0xAA poison start breaks the round arithmetic).
// Co-residency: __launch_bounds__(TPB,4) + grid == 4*256 CUs.
__device__ __forceinline__ void grid_barrier(unsigned* cnt) {
    __syncthreads();
    if (threadIdx.x == 0) {
        __threadfence();  // release: make this block's writes device-visible
        unsigned t = __hip_atomic_fetch_add(cnt, 1u, __ATOMIC_RELEASE, __HIP_MEMORY_SCOPE_AGENT);
        unsigned target = (t / NBLK) * NBLK + NBLK;
        while ((int)(__hip_atomic_load(cnt, __ATOMIC_ACQUIRE, __HIP_MEMORY_SCOPE_AGENT) - target) < 0) {
            __builtin_amdgcn_s_sleep(8);
        }
    }
    __syncthreads();
    __threadfence();  // acquire: invalidate stale L1/L2 before reading remote data
}

__global__ __launch_bounds__(TPB, 4)
void fused_kernel(const float* __restrict__ x, const float* __restrict__ W,
                  const float* __restrict__ b, const int* __restrict__ sf,
                  float* __restrict__ out, float* __restrict__ ws) {
    float* part = ws;                          // [NBLK][C] block partials (16 MiB)
    float* gsum = ws + (size_t)NBLK * C;       // [C]
    unsigned* cnt = (unsigned*)(gsum + C);     // barrier ticket (memset 0 per launch)

    const int t = threadIdx.x;
    const int bidx = blockIdx.x;
    const int r0 = bidx * RPB;
    const f32x4* xv = (const f32x4*)x;

    // ---- Phase 1: column partial sums of my 16-row slice; cache rows 12..15 ----
    // Thread t owns f32x4 column groups {t, 256+t, 512+t, 768+t}.
    f32x4 cache[CROWS][4];
    {
        f32x4 acc[4] = {{0,0,0,0},{0,0,0,0},{0,0,0,0},{0,0,0,0}};
#pragma unroll
        for (int r = 0; r < RPB; ++r) {
#pragma unroll
            for (int k = 0; k < 4; ++k) {
                const f32x4 v = xv[(size_t)(r0 + r) * (C / 4) + k * 256 + t];
                acc[k] += v;
                if (r >= RPB - CROWS) cache[r - (RPB - CROWS)][k] = v;  // static after unroll
            }
        }
        f32x4* pv = (f32x4*)part + (size_t)bidx * (C / 4);
#pragma unroll
        for (int k = 0; k < 4; ++k) pv[k * 256 + t] = acc[k];
    }
    grid_barrier(cnt);

    // ---- Phase 2: fold NBLK partial rows -> gsum (16 blocks) ----
    if (bidx < 16) {
        const int c = bidx * 256 + t;
        float s = 0.f;
#pragma unroll 8
        for (int p = 0; p < NBLK; ++p) s += part[(size_t)p * C + c];
        gsum[c] = s;
    }
    grid_barrier(cnt);

    // ---- Phase 3: s[row] = sigmoid(sf*(dot(W[row,:],gsum)/NROWS + b[row])), 4 rows/block ----
    {
        __shared__ float red[16];
        const f32x4* gv = (const f32x4*)gsum;
#pragma unroll
        for (int rr = 0; rr < 4; ++rr) {
            const int row = bidx * 4 + rr;
            const f32x4* wv = (const f32x4*)(W + (size_t)row * C);
            float acc = 0.f;
#pragma unroll
            for (int k = 0; k < 4; ++k) {
                const f32x4 w = __builtin_nontemporal_load(wv + k * 256 + t);
                const f32x4 g = gv[k * 256 + t];
                acc += w.x * g.x + w.y * g.y + w.z * g.z + w.w * g.w;
            }
#pragma unroll
            for (int off = 32; off > 0; off >>= 1) acc += __shfl_down(acc, off);
            if ((t & 63) == 0) red[(rr << 2) | (t >> 6)] = acc;
        }
        __syncthreads();
        if (t < 4) {
            const int row = bidx * 4 + t;
            const float dot = red[t << 2] + red[(t << 2) | 1] + red[(t << 2) | 2] + red[(t << 2) | 3];
            const float y = dot * (1.0f / NROWS) + b[row];
            const float z = y * (float)sf[0];
            out[(size_t)NROWS * C + row] = 1.0f / (1.0f + __expf(-z));
        }
    }
    grid_barrier(cnt);

    // ---- Phase 4: out[n][c] = x[n][c]*s[c] over my slice; rows 12..15 from regs ----
    {
        const f32x4* sv = (const f32x4*)(out + (size_t)NROWS * C);
        f32x4* ov = (f32x4*)out;
        f32x4 svv[4];
#pragma unroll
        for (int k = 0; k < 4; ++k) svv[k] = sv[k * 256 + t];
#pragma unroll
        for (int r = 0; r < RPB; ++r) {
#pragma unroll
            for (int k = 0; k < 4; ++k) {
                const size_t idx = (size_t)(r0 + r) * (C / 4) + k * 256 + t;
                f32x4 v = (r >= RPB - CROWS) ? cache[r - (RPB - CROWS)][k]
                                             : __builtin_nontemporal_load(xv + idx);
                v *= svv[k];
                __builtin_nontemporal_store(v, ov + idx);
            }
        }
    }
}

extern "C" void kernel_launch(void* const* d_in, const int* in_sizes, int n_in,
                              void* d_out, int out_size, void* d_ws, size_t ws_size,
                              hipStream_t stream) {
    const float* x = (const float*)d_in[0];   // [NROWS, C] fp32
    const float* W = (const float*)d_in[1];   // [C, C] fp32
    const float* b = (const float*)d_in[2];   // [C] fp32
    const int* sf  = (const int*)d_in[3];     // scalar int

    float* out = (float*)d_out;               // [NROWS*C] x_out ++ [C] x_scale
    float* ws  = (float*)d_ws;

    // Barrier counter lives after part[NBLK][C] + gsum[C]; MUST be 0 each call.
    const size_t cnt_off = ((size_t)NBLK * C + C) * sizeof(float);
    hipMemsetAsync((char*)d_ws + cnt_off, 0, sizeof(unsigned), stream);

    fused_kernel<<<NBLK, TPB, 0, stream>>>(x, W, b, sf, out, ws);
}

// Round 6
// 225.683 us; speedup vs baseline: 6.0843x; 6.0843x over previous
//
#include <hip/hip_runtime.h>

#define C 4096
#define NROWS 16384
#define NBLK 256      // one block per CU, all co-resident
#define TPB 1024
#define RPB 64        // rows per block (NROWS/NBLK)

typedef float f32x4 __attribute__((ext_vector_type(4)));

// Grid barrier, R5-bug-fixed:
//  - release: ONE ACQ_REL fetch_add per block (one buffer_wbl2), thread 0 only
//  - spin:    RELAXED agent loads (NO buffer_inv per poll — R5's killer)
//  - acquire: ONE acquire load per block after the spin exits
// Counter must start at a multiple of NBLK -> memsetAsync(0) per launch.
__device__ __forceinline__ void grid_barrier(unsigned* cnt) {
    __syncthreads();  // compiler drains vmcnt per wave before s_barrier
    if (threadIdx.x == 0) {
        unsigned t = __hip_atomic_fetch_add(cnt, 1u, __ATOMIC_ACQ_REL,
                                            __HIP_MEMORY_SCOPE_AGENT);
        const unsigned target = (t / NBLK) * NBLK + NBLK;
        while ((int)(__hip_atomic_load(cnt, __ATOMIC_RELAXED,
                                       __HIP_MEMORY_SCOPE_AGENT) - target) < 0) {
            __builtin_amdgcn_s_sleep(16);
        }
        unsigned v = __hip_atomic_load(cnt, __ATOMIC_ACQUIRE,
                                       __HIP_MEMORY_SCOPE_AGENT);
        asm volatile("" :: "v"(v));  // keep the acquire (and its inv) alive
    }
    __syncthreads();
}

__global__ __launch_bounds__(TPB, 4)   // 16 waves/block -> 4/SIMD -> 1 block/CU
void fused_kernel(const float* __restrict__ x, const float* __restrict__ W,
                  const float* __restrict__ b, const int* __restrict__ sf,
                  float* __restrict__ out, float* __restrict__ ws) {
    float* part = ws;                        // [NBLK][C] partials (4 MiB)
    float* gsum = ws + (size_t)NBLK * C;     // [C]
    unsigned* cnt = (unsigned*)(gsum + C);   // barrier ticket (memset 0 per launch)

    const int t = threadIdx.x;               // 0..1023
    const int bidx = blockIdx.x;             // 0..255
    const int r0 = bidx * RPB;
    const float sf0 = (float)sf[0];

    // ---- Phase 1: column partials of my 64-row slice (plain loads: keep x in L3) ----
    {
        const f32x4* xv = (const f32x4*)x + (size_t)r0 * (C / 4) + t;
        f32x4 acc = {0.f, 0.f, 0.f, 0.f};
#pragma unroll 8
        for (int r = 0; r < RPB; ++r)
            acc += xv[(size_t)r * (C / 4)];
        ((f32x4*)part)[(size_t)bidx * (C / 4) + t] = acc;
    }
    grid_barrier(cnt);

    // ---- Phase 2: fold NBLK partial rows -> gsum (4 blocks, coalesced per p) ----
    if (bidx < 4) {
        const int c = bidx * TPB + t;        // 0..4095
        float s = 0.f;
#pragma unroll 16
        for (int p = 0; p < NBLK; ++p) s += part[(size_t)p * C + c];
        gsum[c] = s;
    }
    grid_barrier(cnt);

    // ---- Phase 3: wave w -> row bidx*16+w: s[row]=sigmoid(sf*(W[row]@gsum/N + b)) ----
    {
        const int wave = t >> 6, lane = t & 63;
        const int row = bidx * 16 + wave;
        const f32x4* wv = (const f32x4*)(W + (size_t)row * C);
        const f32x4* gv = (const f32x4*)gsum;
        float acc = 0.f;
#pragma unroll
        for (int i = 0; i < 16; ++i) {
            const f32x4 w4 = __builtin_nontemporal_load(wv + i * 64 + lane);
            const f32x4 g4 = gv[i * 64 + lane];
            acc += w4.x * g4.x + w4.y * g4.y + w4.z * g4.z + w4.w * g4.w;
        }
#pragma unroll
        for (int off = 32; off; off >>= 1) acc += __shfl_down(acc, off);
        if (lane == 0) {
            const float y = acc * (1.0f / NROWS) + b[row];
            out[(size_t)NROWS * C + row] = 1.0f / (1.0f + __expf(-sf0 * y));
        }
    }
    grid_barrier(cnt);

    // ---- Phase 4: out = x * s over my same 64-row slice (L3-warm re-read) ----
    {
        const f32x4 sc = ((const f32x4*)(out + (size_t)NROWS * C))[t];
        const f32x4* xv = (const f32x4*)x + (size_t)r0 * (C / 4) + t;
        f32x4* ov = (f32x4*)out + (size_t)r0 * (C / 4) + t;
#pragma unroll 4
        for (int r = 0; r < RPB; ++r) {
            f32x4 v = xv[(size_t)r * (C / 4)];
            v *= sc;
            __builtin_nontemporal_store(v, ov + (size_t)r * (C / 4));
        }
    }
}

extern "C" void kernel_launch(void* const* d_in, const int* in_sizes, int n_in,
                              void* d_out, int out_size, void* d_ws, size_t ws_size,
                              hipStream_t stream) {
    const float* x = (const float*)d_in[0];   // [NROWS, C] fp32
    const float* W = (const float*)d_in[1];   // [C, C] fp32
    const float* b = (const float*)d_in[2];   // [C] fp32
    const int* sf  = (const int*)d_in[3];     // scalar int

    float* out = (float*)d_out;               // [NROWS*C] x_out ++ [C] x_scale
    float* ws  = (float*)d_ws;

    const size_t cnt_off = ((size_t)NBLK * C + C) * sizeof(float);
    hipMemsetAsync((char*)d_ws + cnt_off, 0, sizeof(unsigned), stream);

    fused_kernel<<<NBLK, TPB, 0, stream>>>(x, W, b, sf, out, ws);
}